// Round 1
// baseline (1086.189 us; speedup 1.0000x reference)
//
#include <hip/hip_runtime.h>
#include <hip/hip_bf16.h>
#include <math.h>

// ---------------------------------------------------------------------------
// QuantumLayer: 8 qubits, 256-dim state, B=65536.
// Circuit = fixed 256x256 unitary U (params only) applied to real product
// state psi(x). out_q = sum_k sign_q(k) * |(U psi)_k|^2.
//
// Kernel A: build U columns (Wr/Wi, layout [k][j]) in d_ws.
// Kernel B: fused: psi-tile gen (LDS) -> fp32 matvec vs Wr/Wi -> signed
//           probability reduction to 8 outputs per batch element.
// ---------------------------------------------------------------------------

#define NQ   8
#define DIM  256
#define BM   64          // batch tile per block
#define PSI_LD 257       // pad: bank = (lane + j) % 32 -> 2-way (free)

// ---------------- Kernel A: build U from params ----------------------------
__global__ __launch_bounds__(256) void qc_build_u(
    const float* __restrict__ conv_p,   // (2,7,3)
    const float* __restrict__ pool_p,   // (3,3)
    float* __restrict__ Wr,             // [k*256 + j]
    float* __restrict__ Wi) {
  __shared__ float sr[DIM];
  __shared__ float si[DIM];
  const int k   = threadIdx.x;   // amplitude index
  const int col = blockIdx.x;    // basis column j

  sr[k] = (k == col) ? 1.f : 0.f;
  si[k] = 0.f;
  __syncthreads();

  auto rz = [&](float th, int wire) {
    // diag(e^{-i th/2}, e^{+i th/2}); wire w = bit (7-w)
    const int bit = (k >> (7 - wire)) & 1;
    float s, c;
    sincosf(0.5f * th, &s, &c);
    const float fi = bit ? s : -s;
    const float r = sr[k], im = si[k];
    sr[k] = r * c - im * fi;
    si[k] = r * fi + im * c;
    __syncthreads();
  };
  auto ry = [&](float th, int wire) {
    const int bp = 7 - wire, mask = 1 << bp;
    const int bit = (k >> bp) & 1;
    float s, c;
    sincosf(0.5f * th, &s, &c);
    const float mr = sr[k],        mi = si[k];
    const float pr = sr[k ^ mask], pi = si[k ^ mask];
    __syncthreads();
    const float sgn = bit ? s : -s;   // new0 = c*o0 - s*o1 ; new1 = s*o0 + c*o1
    sr[k] = c * mr + sgn * pr;
    si[k] = c * mi + sgn * pi;
    __syncthreads();
  };
  auto cnot = [&](int cw, int tw) {
    const int cb = 7 - cw, tb = 7 - tw;
    const int src = ((k >> cb) & 1) ? (k ^ (1 << tb)) : k;
    const float r = sr[src], im = si[src];
    __syncthreads();
    sr[k] = r; si[k] = im;
    __syncthreads();
  };

  // conv blocks
  for (int l = 0; l < 2; ++l)
    for (int i = 0; i < 7; ++i) {
      const float* p = conv_p + (l * 7 + i) * 3;
      rz(p[0], i);
      ry(p[1], i + 1);
      cnot(i, i + 1);
      ry(p[2], i + 1);
    }
  // pool blocks: p0:(0->4)(1->5)(2->6)(3->7)  p1:(0->2)(1->3)  p2:(0->1)
  const int srcs[7] = {0, 1, 2, 3, 0, 1, 0};
  const int snks[7] = {4, 5, 6, 7, 2, 3, 1};
  const int pidx[7] = {0, 0, 0, 0, 1, 1, 2};
  for (int m = 0; m < 7; ++m) {
    const float* p = pool_p + pidx[m] * 3;
    rz(p[0], srcs[m]);
    ry(p[1], snks[m]);
    cnot(srcs[m], snks[m]);
    ry(p[2], snks[m]);
  }

  Wr[k * DIM + col] = sr[k];
  Wi[k * DIM + col] = si[k];
}

// ---------------- Kernel B: fused psi-gen + matvec + measure ---------------
__global__ __launch_bounds__(256) void qc_main(
    const float* __restrict__ x,    // (B, 8)
    const float* __restrict__ Wr,
    const float* __restrict__ Wi,
    float* __restrict__ out,        // (B, 8)
    int B) {
  __shared__ float psi[BM * PSI_LD];       // 65792 B
  __shared__ float csb[BM][NQ][2];         // 4096 B  (cos, sin per qubit)
  __shared__ float red[4][BM][NQ];         // 8192 B  (per-wave partials)

  const int t  = threadIdx.x;
  const int b0 = blockIdx.x * BM;

  // ---- load x tile, compute cos/sin(x/2) ----
  for (int i = t; i < BM * NQ; i += 256) {
    const float xv = x[(size_t)b0 * NQ + i];
    float s, c;
    sincosf(0.5f * xv, &s, &c);
    csb[i >> 3][i & 7][0] = c;
    csb[i >> 3][i & 7][1] = s;
  }
  __syncthreads();

  // ---- generate psi tile: psi[b][k] = prod_q (bit_q(k) ? s : c) ----
  {
    const int k = t;  // 0..255
    for (int b = 0; b < BM; ++b) {
      float v = 1.f;
#pragma unroll
      for (int q = 0; q < NQ; ++q)
        v *= csb[b][q][(k >> (7 - q)) & 1];
      psi[b * PSI_LD + k] = v;
    }
  }
  __syncthreads();

  // ---- main: each wave handles 64 k-rows for all 64 batch elems ----
  const int wave = t >> 6, lane = t & 63;
  const float* psirow = &psi[lane * PSI_LD];   // this lane's batch element

  float acc[NQ];
#pragma unroll
  for (int q = 0; q < NQ; ++q) acc[q] = 0.f;

  const int kbase = wave * 64;
  for (int kb = 0; kb < 8; ++kb) {             // 8 k-rows per pass
    const int k0 = kbase + kb * 8;
    const float* wr0 = Wr + (size_t)k0 * DIM;
    const float* wi0 = Wi + (size_t)k0 * DIM;
    float fr[8], fi[8];
#pragma unroll
    for (int r = 0; r < 8; ++r) { fr[r] = 0.f; fi[r] = 0.f; }

    for (int j = 0; j < DIM; j += 8) {
      float pv[8];
#pragma unroll
      for (int u = 0; u < 8; ++u) pv[u] = psirow[j + u];
#pragma unroll
      for (int r = 0; r < 8; ++r) {
#pragma unroll
        for (int u = 0; u < 8; ++u) {
          fr[r] = fmaf(wr0[r * DIM + j + u], pv[u], fr[r]);
          fi[r] = fmaf(wi0[r * DIM + j + u], pv[u], fi[r]);
        }
      }
    }
#pragma unroll
    for (int r = 0; r < 8; ++r) {
      const int kidx = k0 + r;
      const float p = fr[r] * fr[r] + fi[r] * fi[r];
#pragma unroll
      for (int q = 0; q < NQ; ++q)
        acc[q] += ((kidx >> (7 - q)) & 1) ? -p : p;
    }
  }

  // ---- cross-wave reduction ----
#pragma unroll
  for (int q = 0; q < NQ; ++q) red[wave][lane][q] = acc[q];
  __syncthreads();
  for (int i = t; i < BM * NQ; i += 256) {
    const int b = i >> 3, q = i & 7;
    const float v = red[0][b][q] + red[1][b][q] + red[2][b][q] + red[3][b][q];
    out[(size_t)(b0 + b) * NQ + q] = v;
  }
}

// ---------------------------------------------------------------------------
extern "C" void kernel_launch(void* const* d_in, const int* in_sizes, int n_in,
                              void* d_out, int out_size, void* d_ws, size_t ws_size,
                              hipStream_t stream) {
  const float* x      = (const float*)d_in[0];
  const float* conv_p = (const float*)d_in[1];
  const float* pool_p = (const float*)d_in[2];
  float* out = (float*)d_out;

  float* Wr = (float*)d_ws;              // 256*256 fp32
  float* Wi = Wr + DIM * DIM;            // 256*256 fp32

  const int B = in_sizes[0] / NQ;        // 65536

  qc_build_u<<<DIM, DIM, 0, stream>>>(conv_p, pool_p, Wr, Wi);
  qc_main<<<B / BM, 256, 0, stream>>>(x, Wr, Wi, out, B);
}